// Round 6
// baseline (690.812 us; speedup 1.0000x reference)
//
#include <hip/hip_runtime.h>
#include <hip/hip_bf16.h>
#include <stdint.h>

// SparseMoE: B=8,S=2048 -> 16384 tokens, D=512, E=10, H=2048, top-2.
// Sparse expert-grouped two-pass bf16 MFMA GEMM. Router in fp32 (no shuffles).
// R2: chunked-XCD block swizzle (T1).
// R3: T2 XOR bank-swizzle, raw-barrier K-loop.
// R4/R5: 2-phase drain-to-zero — measured 70% stall (HBM-latency A-stream).
// R6: T4 counted-vmcnt depth-4 ring pipeline, BK=32. Stage tile kt+3 while
//     computing kt; vmcnt(8) allows 2 tiles in flight across barriers ->
//     ~3 iterations (~1200 cyc) of latency slack per tile. Never vmcnt(0)
//     in the main loop. One barrier per K-tile.

#define N_TOK 16384
#define DIM 512
#define NEXP 10
#define HID 2048
#define BM 256
#define BN 256
#define BK 32
#define TILE_EL (BM*BK)               // 8192 elems = 16 KB
#define MAXSLOT (2*N_TOK + NEXP*BM)   // 35328 (each expert padded to 256)
#define NMB (MAXSLOT/BM)              // 138
#define RT_TOK 32                     // router tokens per block
#define NBN1 (HID/BN)                 // 8
#define NBN2 (DIM/BN)                 // 2

typedef __attribute__((ext_vector_type(8))) short bf16x8;   // 8 bf16 = 4 VGPR
typedef __attribute__((ext_vector_type(4))) float f32x4;

__device__ __forceinline__ unsigned short f2bf(float v) {
  __hip_bfloat16 h = __float2bfloat16(v);
  return *reinterpret_cast<unsigned short*>(&h);
}

__device__ __forceinline__ void gload_lds16(const void* g, void* l) {
  __builtin_amdgcn_global_load_lds(
      (__attribute__((address_space(1))) void*)g,
      (__attribute__((address_space(3))) void*)l, 16, 0, 0);
}

// bijective chunked XCD remap (m204)
__device__ __forceinline__ int xcd_chunk(int b, int nwg) {
  int q = nwg >> 3, r = nwg & 7;
  int xcd = b & 7, slot = b >> 3;
  return (xcd < r) ? (xcd*(q+1) + slot) : (r*(q+1) + (xcd-r)*q + slot);
}

#define VM8 asm volatile("s_waitcnt vmcnt(8)" ::: "memory")
#define VM4 asm volatile("s_waitcnt vmcnt(4)" ::: "memory")
#define VM0 asm volatile("s_waitcnt vmcnt(0)" ::: "memory")
#define BARX { __builtin_amdgcn_s_barrier(); __builtin_amdgcn_sched_barrier(0); }

// ---------------- prepack ----------------
__global__ void k_cvt_x(const float* __restrict__ x, unsigned short* __restrict__ xb) {
  size_t i = (size_t)blockIdx.x * 256 + threadIdx.x;   // one per 8 elements
  const float4* xp = (const float4*)x;
  float4 a = xp[2*i], b = xp[2*i+1];
  union { unsigned short us[8]; uint4 u4; } p;
  p.us[0]=f2bf(a.x); p.us[1]=f2bf(a.y); p.us[2]=f2bf(a.z); p.us[3]=f2bf(a.w);
  p.us[4]=f2bf(b.x); p.us[5]=f2bf(b.y); p.us[6]=f2bf(b.z); p.us[7]=f2bf(b.w);
  ((uint4*)xb)[i] = p.u4;
}

__global__ void k_cvt_router_w(const float* __restrict__ Wr, const float* __restrict__ Wn,
                               float* __restrict__ wrt, float* __restrict__ wnt) {
  int i = blockIdx.x * 256 + threadIdx.x;
  if (i < NEXP*DIM) {
    int e = i / DIM, d = i % DIM;
    wrt[i] = Wr[d*NEXP + e];
    wnt[i] = Wn[d*NEXP + e];
  }
}

// in [E][R][C] f32 -> out [E][C][R] bf16 (LDS-tiled 64x64 transpose, vec writes)
__global__ void k_transpose(const float* __restrict__ in, unsigned short* __restrict__ outp,
                            int R, int C) {
  __shared__ float tile[64][65];
  int nTR = R >> 6, nTC = C >> 6;
  int b = blockIdx.x;
  int tilesPerE = nTR * nTC;
  int e = b / tilesPerE;
  int t = b % tilesPerE;
  int rb = t / nTC, cb = t % nTC;
  int tr = threadIdx.x >> 6, tc = threadIdx.x & 63;
  const float* ip = in + ((size_t)e*R + (size_t)rb*64) * C + cb*64;
  #pragma unroll
  for (int p = 0; p < 16; ++p)
    tile[p*4 + tr][tc] = ip[(size_t)(p*4 + tr)*C + tc];
  __syncthreads();
  unsigned short* op = outp + ((size_t)e*C + (size_t)cb*64) * R + rb*64;
  int ro = threadIdx.x >> 2;            // out row 0..63
  int cc = (threadIdx.x & 3) * 16;      // out col chunk
  union { unsigned short us[8]; bf16x8 v; } pk;
  #pragma unroll
  for (int half = 0; half < 2; ++half) {
    #pragma unroll
    for (int j = 0; j < 8; ++j) pk.us[j] = f2bf(tile[cc + half*8 + j][ro]);
    *(bf16x8*)&op[(size_t)ro*R + cc + half*8] = pk.v;
  }
}

// ---------------- router (fp32, shuffle-free) ----------------
__global__ __launch_bounds__(256) void k_router2(
    const float* __restrict__ x, const float* __restrict__ noise,
    const float* __restrict__ wrt, const float* __restrict__ wnt,
    const float* __restrict__ br, const float* __restrict__ bnb,
    int* __restrict__ top_idx, float* __restrict__ top_gate, int* __restrict__ counts) {
  __shared__ float part[8][RT_TOK][21];
  __shared__ float red[RT_TOK][21];
  __shared__ float vsh[RT_TOK][10];
  int tid = threadIdx.x;
  int tl = tid & 31;          // token-local
  int g  = tid >> 5;          // d-group 0..7
  int tok = blockIdx.x * RT_TOK + tl;

  const float4* xr = (const float4*)(x + (size_t)tok*DIM + g*64);
  float acc[20];
  #pragma unroll
  for (int j = 0; j < 20; ++j) acc[j] = 0.f;

  #pragma unroll 4
  for (int c = 0; c < 16; ++c) {
    float4 xv = xr[c];
    int d = g*64 + c*4;
    #pragma unroll
    for (int e = 0; e < NEXP; ++e) {
      float4 a = *(const float4*)(wrt + e*DIM + d);
      float4 b = *(const float4*)(wnt + e*DIM + d);
      acc[e]      += xv.x*a.x + xv.y*a.y + xv.z*a.z + xv.w*a.w;
      acc[10+e]   += xv.x*b.x + xv.y*b.y + xv.z*b.z + xv.w*b.w;
    }
  }
  #pragma unroll
  for (int j = 0; j < 20; ++j) part[g][tl][j] = acc[j];
  __syncthreads();

  for (int o = tid; o < RT_TOK*20; o += 256) {
    int t2 = o / 20, j = o % 20;
    float s = 0.f;
    #pragma unroll
    for (int gg = 0; gg < 8; ++gg) s += part[gg][t2][j];
    red[t2][j] = s;
  }
  __syncthreads();

  for (int o = tid; o < RT_TOK*NEXP; o += 256) {
    int t2 = o / NEXP, e = o % NEXP;
    float nl = red[t2][10+e] + bnb[e];
    float sp = (nl > 20.f) ? nl : log1pf(expf(nl));
    vsh[t2][e] = red[t2][e] + br[e]
               + noise[(size_t)(blockIdx.x*RT_TOK + t2)*NEXP + e] * sp;
  }
  __syncthreads();

  if (tid < RT_TOK) {
    int t2 = tid;
    float v0 = -1e30f, v1 = -1e30f; int i0 = 0, i1 = 0;
    #pragma unroll
    for (int e = 0; e < NEXP; ++e) {
      float v = vsh[t2][e];
      if (v > v0) { v1 = v0; i1 = i0; v0 = v; i0 = e; }
      else if (v > v1) { v1 = v; i1 = e; }
    }
    float ev = expf(v1 - v0);
    float g0 = 1.f / (1.f + ev);
    float g1 = ev / (1.f + ev);
    int tk = blockIdx.x * RT_TOK + t2;
    top_idx[tk*2] = i0; top_idx[tk*2+1] = i1;
    top_gate[tk*2] = g0; top_gate[tk*2+1] = g1;
    atomicAdd(&counts[i0], 1);
    atomicAdd(&counts[i1], 1);
  }
}

__global__ void k_offsets(const int* __restrict__ counts, int* __restrict__ cursors,
                          int* __restrict__ offs) {
  if (threadIdx.x == 0 && blockIdx.x == 0) {
    int acc = 0;
    for (int e = 0; e < NEXP; ++e) {
      offs[e] = acc; cursors[e] = acc;
      acc += ((counts[e] + BM - 1) / BM) * BM;   // pad to BM=256
    }
    offs[NEXP] = acc;
  }
}

__global__ void k_scatter(const int* __restrict__ top_idx, const float* __restrict__ top_gate,
                          int* __restrict__ cursors, int* __restrict__ slot_token,
                          float* __restrict__ slot_gate) {
  int t = blockIdx.x * 256 + threadIdx.x;
  if (t < N_TOK) {
    #pragma unroll
    for (int k = 0; k < 2; ++k) {
      int e = top_idx[t*2 + k];
      int pos = atomicAdd(&cursors[e], 1);
      slot_token[pos] = t;
      slot_gate[pos] = top_gate[t*2 + k];
    }
  }
}

// Shared compute macro: 12 swizzled ds_read_b128 + 32 MFMA, setprio-wrapped.
#define COMPUTE(cur) {                                                          \
  const unsigned short* Ab = As[cur]; const unsigned short* Bb = Bs[cur];       \
  bf16x8 a[8], b[4];                                                            \
  _Pragma("unroll")                                                             \
  for (int m = 0; m < 8; ++m) a[m] = *(const bf16x8*)&Ab[(arow + m*16)*BK + pso]; \
  _Pragma("unroll")                                                             \
  for (int n = 0; n < 4; ++n) b[n] = *(const bf16x8*)&Bb[(brow + n*16)*BK + pso]; \
  __builtin_amdgcn_s_setprio(1);                                                \
  _Pragma("unroll")                                                             \
  for (int m = 0; m < 8; ++m)                                                   \
    _Pragma("unroll")                                                           \
    for (int n = 0; n < 4; ++n)                                                 \
      acc[m][n] = __builtin_amdgcn_mfma_f32_16x16x32_bf16(a[m], b[n], acc[m][n], 0,0,0); \
  __builtin_amdgcn_s_setprio(0); }

// ---------------- GEMM1: h = relu(gather(x) @ W1[e] + b1[e]) ----------------
// 512 threads = 8 waves (2M x 4N); ring-4 K-tile pipeline, BK=32.
__global__ __launch_bounds__(512, 2) void k_gemm1(
    const unsigned short* __restrict__ xb, const unsigned short* __restrict__ w1t,
    const float* __restrict__ b1, const int* __restrict__ slot_token,
    const int* __restrict__ offs, unsigned short* __restrict__ h) {
  __shared__ unsigned short As[4][TILE_EL];   // 4 x 16 KB
  __shared__ unsigned short Bs[4][TILE_EL];   // 4 x 16 KB
  int w = xcd_chunk(blockIdx.x, NMB*NBN1);
  int bm = w / NBN1, bn = w % NBN1;
  int tid = threadIdx.x, wid = tid >> 6, lane = tid & 63;
  int s0 = bm * BM;
  int e = 0;
  #pragma unroll
  for (int i = 1; i < NEXP; ++i) if (s0 >= offs[i]) e = i;

  int trow = tid >> 2;                       // staging row (0..127), +128 for l=1
  int t0 = slot_token[s0 + trow];
  int t1 = slot_token[s0 + trow + 128];
  int tok0 = t0 < 0 ? 0 : t0;
  int tok1 = t1 < 0 ? 0 : t1;
  // stage-side swizzled source col-slot (lane-only): sg = (t&3)^(row&3)^((row>>2)&3)
  int sg8 = (((tid & 3) ^ ((tid >> 2) & 3) ^ ((tid >> 4) & 3)) * 8);
  const unsigned short* w1te = w1t + ((size_t)e*HID + (size_t)bn*BN) * DIM;

  f32x4 acc[8][4];
  #pragma unroll
  for (int m=0;m<8;m++)
    #pragma unroll
    for (int n=0;n<4;n++) acc[m][n] = (f32x4){0.f,0.f,0.f,0.f};

  int wr = wid >> 2, wc = wid & 3;
  int arow = wr*128 + (lane & 15);
  int brow = wc*64  + (lane & 15);
  // read-side physical slot: (lane>>4) ^ (row&3) ^ ((row>>2)&3) -> lane-only
  int pso = (((lane >> 4) ^ (lane & 3) ^ ((lane >> 2) & 3)) * 8);

  #define STAGE1(rs, ti) {                                                     \
    int k0_ = (ti)*BK + sg8;                                                   \
    gload_lds16(xb  + (size_t)tok0*DIM + k0_,            &As[rs][tid*8]);      \
    gload_lds16(xb  + (size_t)tok1*DIM + k0_,            &As[rs][tid*8 + 4096]); \
    gload_lds16(w1te + (size_t)trow*DIM + k0_,           &Bs[rs][tid*8]);      \
    gload_lds16(w1te + (size_t)(trow + 128)*DIM + k0_,   &Bs[rs][tid*8 + 4096]); }

  STAGE1(0, 0); STAGE1(1, 1); STAGE1(2, 2);
  const int NT = DIM/BK;                      // 16
  for (int kt = 0; kt < NT-3; ++kt) {
    VM8; BARX;
    STAGE1((kt+3)&3, kt+3);
    COMPUTE(kt&3);
    __builtin_amdgcn_sched_barrier(0);
  }
  VM8; BARX; COMPUTE((NT-3)&3); __builtin_amdgcn_sched_barrier(0);
  VM4; BARX; COMPUTE((NT-2)&3); __builtin_amdgcn_sched_barrier(0);
  VM0; BARX; COMPUTE((NT-1)&3);
  #undef STAGE1

  #pragma unroll
  for (int m=0;m<8;m++){
    int row0 = wr*128 + m*16 + (lane>>4)*4;
    #pragma unroll
    for (int n=0;n<4;n++){
      int col = bn*BN + wc*64 + n*16 + (lane&15);
      float bias = b1[e*HID + col];
      #pragma unroll
      for (int r=0;r<4;r++){
        float v = acc[m][n][r] + bias;
        v = v > 0.f ? v : 0.f;
        h[(size_t)(s0 + row0 + r)*HID + col] = f2bf(v);
      }
    }
  }
}

// ---------------- GEMM2: out[tok] += gate * (h @ W2[e] + b2[e]) ----------------
__global__ __launch_bounds__(512, 2) void k_gemm2(
    const unsigned short* __restrict__ h, const unsigned short* __restrict__ w2t,
    const float* __restrict__ b2, const int* __restrict__ slot_token,
    const float* __restrict__ slot_gate, const int* __restrict__ offs,
    float* __restrict__ out) {
  __shared__ unsigned short As[4][TILE_EL];
  __shared__ unsigned short Bs[4][TILE_EL];
  int w = xcd_chunk(blockIdx.x, NMB*NBN2);
  int bm = w / NBN2, bn = w % NBN2;
  int tid = threadIdx.x, wid = tid >> 6, lane = tid & 63;
  int s0 = bm * BM;
  int e = 0;
  #pragma unroll
  for (int i = 1; i < NEXP; ++i) if (s0 >= offs[i]) e = i;
  int trow = tid >> 2;
  int sg8 = (((tid & 3) ^ ((tid >> 2) & 3) ^ ((tid >> 4) & 3)) * 8);
  const unsigned short* w2te = w2t + ((size_t)e*DIM + (size_t)bn*BN) * HID;

  f32x4 acc[8][4];
  #pragma unroll
  for (int m=0;m<8;m++)
    #pragma unroll
    for (int n=0;n<4;n++) acc[m][n] = (f32x4){0.f,0.f,0.f,0.f};

  int wr = wid >> 2, wc = wid & 3;
  int arow = wr*128 + (lane & 15);
  int brow = wc*64  + (lane & 15);
  int pso = (((lane >> 4) ^ (lane & 3) ^ ((lane >> 2) & 3)) * 8);

  #define STAGE2(rs, ti) {                                                      \
    int k0_ = (ti)*BK + sg8;                                                    \
    gload_lds16(h + (size_t)(s0 + trow)*HID + k0_,        &As[rs][tid*8]);      \
    gload_lds16(h + (size_t)(s0 + trow + 128)*HID + k0_,  &As[rs][tid*8 + 4096]); \
    gload_lds16(w2te + (size_t)trow*HID + k0_,            &Bs[rs][tid*8]);      \
    gload_lds16(w2te + (size_t)(trow + 128)*HID + k0_,    &Bs[rs][tid*8 + 4096]); }

  STAGE2(0, 0); STAGE2(1, 1); STAGE2(2, 2);
  const int NT = HID/BK;                      // 64
  for (int kt = 0; kt < NT-3; ++kt) {
    VM8; BARX;
    STAGE2((kt+3)&3, kt+3);
    COMPUTE(kt&3);
    __builtin_amdgcn_sched_barrier(0);
  }
  VM8; BARX; COMPUTE((NT-3)&3); __builtin_amdgcn_sched_barrier(0);
  VM4; BARX; COMPUTE((NT-2)&3); __builtin_amdgcn_sched_barrier(0);
  VM0; BARX; COMPUTE((NT-1)&3);
  #undef STAGE2

  #pragma unroll
  for (int m=0;m<8;m++){
    int rb_ = s0 + wr*128 + m*16 + (lane>>4)*4;
    #pragma unroll
    for (int r=0;r<4;r++){
      int slot = rb_ + r;
      int tok = slot_token[slot];
      if (tok < 0) continue;
      float g = slot_gate[slot];
      #pragma unroll
      for (int n=0;n<4;n++){
        int col = bn*BN + wc*64 + n*16 + (lane&15);
        float v = (acc[m][n][r] + b2[e*DIM + col]) * g;
        atomicAdd(&out[(size_t)tok*DIM + col], v);  // exactly 2 adds/elem -> deterministic
      }
    }
  }
}

extern "C" void kernel_launch(void* const* d_in, const int* in_sizes, int n_in,
                              void* d_out, int out_size, void* d_ws, size_t ws_size,
                              hipStream_t stream) {
  const float* x   = (const float*)d_in[0];
  const float* noi = (const float*)d_in[1];
  const float* Wr  = (const float*)d_in[2];
  const float* br  = (const float*)d_in[3];
  const float* Wn  = (const float*)d_in[4];
  const float* bnb = (const float*)d_in[5];
  const float* W1  = (const float*)d_in[6];
  const float* b1  = (const float*)d_in[7];
  const float* W2  = (const float*)d_in[8];
  const float* b2  = (const float*)d_in[9];
  float* out = (float*)d_out;
  (void)in_sizes; (void)n_in; (void)ws_size;

  char* ws = (char*)d_ws;
  size_t off = 0;
  auto alloc = [&](size_t bytes) -> void* {
    void* p = ws + off; off += (bytes + 255) & ~(size_t)255; return p;
  };
  unsigned short* w1t  = (unsigned short*)alloc((size_t)NEXP*HID*DIM*2);
  unsigned short* w2t  = (unsigned short*)alloc((size_t)NEXP*DIM*HID*2);
  unsigned short* xb   = (unsigned short*)alloc((size_t)N_TOK*DIM*2);
  unsigned short* hbuf = (unsigned short*)alloc((size_t)MAXSLOT*HID*2);
  float* wrt = (float*)alloc(NEXP*DIM*4);
  float* wnt = (float*)alloc(NEXP*DIM*4);
  int*   top_idx  = (int*)alloc(N_TOK*2*4);
  float* top_gate = (float*)alloc(N_TOK*2*4);
  int*   slot_token = (int*)alloc((size_t)MAXSLOT*4);
  float* slot_gate  = (float*)alloc((size_t)MAXSLOT*4);
  int*   ctrl = (int*)alloc(64*4);
  int* counts  = ctrl;        // [10]
  int* cursors = ctrl + 10;   // [10]
  int* offs    = ctrl + 20;   // [11]

  hipMemsetAsync(out, 0, (size_t)out_size*4, stream);
  hipMemsetAsync(ctrl, 0, 64*4, stream);
  hipMemsetAsync(slot_token, 0xFF, (size_t)MAXSLOT*4, stream);  // -1 fill

  k_cvt_x<<<(N_TOK*DIM/8)/256, 256, 0, stream>>>(x, xb);
  k_cvt_router_w<<<(NEXP*DIM+255)/256, 256, 0, stream>>>(Wr, Wn, wrt, wnt);
  k_transpose<<<NEXP*(DIM/64)*(HID/64), 256, 0, stream>>>(W1, w1t, DIM, HID);
  k_transpose<<<NEXP*(HID/64)*(DIM/64), 256, 0, stream>>>(W2, w2t, HID, DIM);
  k_router2<<<N_TOK/RT_TOK, 256, 0, stream>>>(x, noi, wrt, wnt, br, bnb, top_idx, top_gate, counts);
  k_offsets<<<1, 64, 0, stream>>>(counts, cursors, offs);
  k_scatter<<<(N_TOK+255)/256, 256, 0, stream>>>(top_idx, top_gate, cursors, slot_token, slot_gate);
  k_gemm1<<<NMB*NBN1, 512, 0, stream>>>(xb, w1t, b1, slot_token, offs, hbuf);
  k_gemm2<<<NMB*NBN2, 512, 0, stream>>>(hbuf, w2t, b2, slot_token, slot_gate, offs, out);
}

// Round 7
// 538.445 us; speedup vs baseline: 1.2830x; 1.2830x over previous
//
#include <hip/hip_runtime.h>
#include <hip/hip_bf16.h>
#include <stdint.h>

// SparseMoE: B=8,S=2048 -> 16384 tokens, D=512, E=10, H=2048, top-2.
// Sparse expert-grouped two-pass bf16 MFMA GEMM. Router in fp32 (no shuffles).
// R2: chunked-XCD block swizzle (T1).
// R3/R4: T2 XOR bank-swizzle (conflicts 0), dbuf experiments.
// R5/R6: bigger tiles / ring pipeline -> REGRESSED (1 block/CU, latency bare).
// R7: m97 recipe — 128x128/BK64, SINGLE 32KB LDS buffer, __syncthreads
//     2-barrier K-loop, __launch_bounds__(256,4) -> 4-5 blocks/CU so wave-level
//     TLP hides the staging latency (m114). Keep T1 + T2.

#define N_TOK 16384
#define DIM 512
#define NEXP 10
#define HID 2048
#define BM 128
#define BN 128
#define BK 64
#define MAXSLOT (2*N_TOK + NEXP*BM)   // 34048 (each expert padded to 128)
#define NMB (MAXSLOT/BM)              // 266
#define RT_TOK 32                     // router tokens per block
#define NBN1 (HID/BN)                 // 16
#define NBN2 (DIM/BN)                 // 4

typedef __attribute__((ext_vector_type(8))) short bf16x8;   // 8 bf16 = 4 VGPR
typedef __attribute__((ext_vector_type(4))) float f32x4;

__device__ __forceinline__ unsigned short f2bf(float v) {
  __hip_bfloat16 h = __float2bfloat16(v);
  return *reinterpret_cast<unsigned short*>(&h);
}

__device__ __forceinline__ void gload_lds16(const void* g, void* l) {
  __builtin_amdgcn_global_load_lds(
      (__attribute__((address_space(1))) void*)g,
      (__attribute__((address_space(3))) void*)l, 16, 0, 0);
}

// bijective chunked XCD remap (m204)
__device__ __forceinline__ int xcd_chunk(int b, int nwg) {
  int q = nwg >> 3, r = nwg & 7;
  int xcd = b & 7, slot = b >> 3;
  return (xcd < r) ? (xcd*(q+1) + slot) : (r*(q+1) + (xcd-r)*q + slot);
}

// ---------------- prepack ----------------
__global__ void k_cvt_x(const float* __restrict__ x, unsigned short* __restrict__ xb) {
  size_t i = (size_t)blockIdx.x * 256 + threadIdx.x;   // one per 8 elements
  const float4* xp = (const float4*)x;
  float4 a = xp[2*i], b = xp[2*i+1];
  union { unsigned short us[8]; uint4 u4; } p;
  p.us[0]=f2bf(a.x); p.us[1]=f2bf(a.y); p.us[2]=f2bf(a.z); p.us[3]=f2bf(a.w);
  p.us[4]=f2bf(b.x); p.us[5]=f2bf(b.y); p.us[6]=f2bf(b.z); p.us[7]=f2bf(b.w);
  ((uint4*)xb)[i] = p.u4;
}

__global__ void k_cvt_router_w(const float* __restrict__ Wr, const float* __restrict__ Wn,
                               float* __restrict__ wrt, float* __restrict__ wnt) {
  int i = blockIdx.x * 256 + threadIdx.x;
  if (i < NEXP*DIM) {
    int e = i / DIM, d = i % DIM;
    wrt[i] = Wr[d*NEXP + e];
    wnt[i] = Wn[d*NEXP + e];
  }
}

// in [E][R][C] f32 -> out [E][C][R] bf16 (LDS-tiled 64x64 transpose, vec writes)
__global__ void k_transpose(const float* __restrict__ in, unsigned short* __restrict__ outp,
                            int R, int C) {
  __shared__ float tile[64][65];
  int nTR = R >> 6, nTC = C >> 6;
  int b = blockIdx.x;
  int tilesPerE = nTR * nTC;
  int e = b / tilesPerE;
  int t = b % tilesPerE;
  int rb = t / nTC, cb = t % nTC;
  int tr = threadIdx.x >> 6, tc = threadIdx.x & 63;
  const float* ip = in + ((size_t)e*R + (size_t)rb*64) * C + cb*64;
  #pragma unroll
  for (int p = 0; p < 16; ++p)
    tile[p*4 + tr][tc] = ip[(size_t)(p*4 + tr)*C + tc];
  __syncthreads();
  unsigned short* op = outp + ((size_t)e*C + (size_t)cb*64) * R + rb*64;
  int ro = threadIdx.x >> 2;            // out row 0..63
  int cc = (threadIdx.x & 3) * 16;      // out col chunk
  union { unsigned short us[8]; bf16x8 v; } pk;
  #pragma unroll
  for (int half = 0; half < 2; ++half) {
    #pragma unroll
    for (int j = 0; j < 8; ++j) pk.us[j] = f2bf(tile[cc + half*8 + j][ro]);
    *(bf16x8*)&op[(size_t)ro*R + cc + half*8] = pk.v;
  }
}

// ---------------- router (fp32, shuffle-free) ----------------
__global__ __launch_bounds__(256) void k_router2(
    const float* __restrict__ x, const float* __restrict__ noise,
    const float* __restrict__ wrt, const float* __restrict__ wnt,
    const float* __restrict__ br, const float* __restrict__ bnb,
    int* __restrict__ top_idx, float* __restrict__ top_gate, int* __restrict__ counts) {
  __shared__ float part[8][RT_TOK][21];
  __shared__ float red[RT_TOK][21];
  __shared__ float vsh[RT_TOK][10];
  int tid = threadIdx.x;
  int tl = tid & 31;          // token-local
  int g  = tid >> 5;          // d-group 0..7
  int tok = blockIdx.x * RT_TOK + tl;

  const float4* xr = (const float4*)(x + (size_t)tok*DIM + g*64);
  float acc[20];
  #pragma unroll
  for (int j = 0; j < 20; ++j) acc[j] = 0.f;

  #pragma unroll 4
  for (int c = 0; c < 16; ++c) {
    float4 xv = xr[c];
    int d = g*64 + c*4;
    #pragma unroll
    for (int e = 0; e < NEXP; ++e) {
      float4 a = *(const float4*)(wrt + e*DIM + d);
      float4 b = *(const float4*)(wnt + e*DIM + d);
      acc[e]      += xv.x*a.x + xv.y*a.y + xv.z*a.z + xv.w*a.w;
      acc[10+e]   += xv.x*b.x + xv.y*b.y + xv.z*b.z + xv.w*b.w;
    }
  }
  #pragma unroll
  for (int j = 0; j < 20; ++j) part[g][tl][j] = acc[j];
  __syncthreads();

  for (int o = tid; o < RT_TOK*20; o += 256) {
    int t2 = o / 20, j = o % 20;
    float s = 0.f;
    #pragma unroll
    for (int gg = 0; gg < 8; ++gg) s += part[gg][t2][j];
    red[t2][j] = s;
  }
  __syncthreads();

  for (int o = tid; o < RT_TOK*NEXP; o += 256) {
    int t2 = o / NEXP, e = o % NEXP;
    float nl = red[t2][10+e] + bnb[e];
    float sp = (nl > 20.f) ? nl : log1pf(expf(nl));
    vsh[t2][e] = red[t2][e] + br[e]
               + noise[(size_t)(blockIdx.x*RT_TOK + t2)*NEXP + e] * sp;
  }
  __syncthreads();

  if (tid < RT_TOK) {
    int t2 = tid;
    float v0 = -1e30f, v1 = -1e30f; int i0 = 0, i1 = 0;
    #pragma unroll
    for (int e = 0; e < NEXP; ++e) {
      float v = vsh[t2][e];
      if (v > v0) { v1 = v0; i1 = i0; v0 = v; i0 = e; }
      else if (v > v1) { v1 = v; i1 = e; }
    }
    float ev = expf(v1 - v0);
    float g0 = 1.f / (1.f + ev);
    float g1 = ev / (1.f + ev);
    int tk = blockIdx.x * RT_TOK + t2;
    top_idx[tk*2] = i0; top_idx[tk*2+1] = i1;
    top_gate[tk*2] = g0; top_gate[tk*2+1] = g1;
    atomicAdd(&counts[i0], 1);
    atomicAdd(&counts[i1], 1);
  }
}

__global__ void k_offsets(const int* __restrict__ counts, int* __restrict__ cursors,
                          int* __restrict__ offs) {
  if (threadIdx.x == 0 && blockIdx.x == 0) {
    int acc = 0;
    for (int e = 0; e < NEXP; ++e) {
      offs[e] = acc; cursors[e] = acc;
      acc += ((counts[e] + BM - 1) / BM) * BM;   // pad to BM=128
    }
    offs[NEXP] = acc;
  }
}

__global__ void k_scatter(const int* __restrict__ top_idx, const float* __restrict__ top_gate,
                          int* __restrict__ cursors, int* __restrict__ slot_token,
                          float* __restrict__ slot_gate) {
  int t = blockIdx.x * 256 + threadIdx.x;
  if (t < N_TOK) {
    #pragma unroll
    for (int k = 0; k < 2; ++k) {
      int e = top_idx[t*2 + k];
      int pos = atomicAdd(&cursors[e], 1);
      slot_token[pos] = t;
      slot_gate[pos] = top_gate[t*2 + k];
    }
  }
}

// ---------------- GEMM1: h = relu(gather(x) @ W1[e] + b1[e]) ----------------
// m97 structure: single 32KB LDS buffer, 2-barrier K-loop, high occupancy.
__global__ __launch_bounds__(256, 4) void k_gemm1(
    const unsigned short* __restrict__ xb, const unsigned short* __restrict__ w1t,
    const float* __restrict__ b1, const int* __restrict__ slot_token,
    const int* __restrict__ offs, unsigned short* __restrict__ h) {
  __shared__ unsigned short As[BM*BK];   // 16 KB
  __shared__ unsigned short Bs[BN*BK];   // 16 KB
  int w = xcd_chunk(blockIdx.x, NMB*NBN1);
  int bm = w / NBN1, bn = w % NBN1;
  int tid = threadIdx.x, wid = tid >> 6, lane = tid & 63;
  int s0 = bm * BM;
  int e = 0;
  #pragma unroll
  for (int i = 1; i < NEXP; ++i) if (s0 >= offs[i]) e = i;

  int tokA[4];
  #pragma unroll
  for (int i = 0; i < 4; ++i) {
    int r = (i*4 + wid)*8 + (lane >> 3);
    int t = slot_token[s0 + r];
    tokA[i] = t < 0 ? 0 : t;
  }
  // T2 swizzle (R4-verified, conflicts=0): physical slot (lane&7) of row r
  // holds logical col slot (lane&7)^(r&7); r&7 == lane>>3 during staging.
  int kcs = ((lane & 7) ^ (lane >> 3)) * 8;     // swizzled global col (elements)
  int ldst = (lane & 7) * 8;                    // linear LDS col (elements)
  const unsigned short* w1te = w1t + ((size_t)e*HID + (size_t)bn*BN) * DIM;

  f32x4 acc[4][4];
  #pragma unroll
  for (int m=0;m<4;m++)
    #pragma unroll
    for (int n=0;n<4;n++) acc[m][n] = (f32x4){0.f,0.f,0.f,0.f};

  int wr = wid >> 1, wc = wid & 1;
  int xr = (lane & 7) * 8;                      // read-side XOR term: (row&7)*8

  for (int kt = 0; kt < DIM/BK; ++kt) {
    int k0 = kt * BK;
    #pragma unroll
    for (int i = 0; i < 4; ++i) {
      int r = (i*4 + wid)*8 + (lane >> 3);
      gload_lds16(xb + (size_t)tokA[i]*DIM + k0 + kcs, &As[r*BK + ldst]);
      gload_lds16(w1te + (size_t)r*DIM + k0 + kcs, &Bs[r*BK + ldst]);
    }
    __syncthreads();
    #pragma unroll
    for (int ks = 0; ks < 2; ++ks) {
      int kk = (ks*32 + (lane >> 4)*8) ^ xr;    // physical (swizzled) col
      bf16x8 a[4], b[4];
      #pragma unroll
      for (int m=0;m<4;m++) a[m] = *(const bf16x8*)&As[(wr*64 + m*16 + (lane&15))*BK + kk];
      #pragma unroll
      for (int n=0;n<4;n++) b[n] = *(const bf16x8*)&Bs[(wc*64 + n*16 + (lane&15))*BK + kk];
      #pragma unroll
      for (int m=0;m<4;m++)
        #pragma unroll
        for (int n=0;n<4;n++)
          acc[m][n] = __builtin_amdgcn_mfma_f32_16x16x32_bf16(a[m], b[n], acc[m][n], 0,0,0);
    }
    __syncthreads();
  }

  #pragma unroll
  for (int m=0;m<4;m++){
    int row0 = wr*64 + m*16 + (lane>>4)*4;
    #pragma unroll
    for (int n=0;n<4;n++){
      int col = bn*BN + wc*64 + n*16 + (lane&15);
      float bias = b1[e*HID + col];
      #pragma unroll
      for (int r=0;r<4;r++){
        float v = acc[m][n][r] + bias;
        v = v > 0.f ? v : 0.f;
        h[(size_t)(s0 + row0 + r)*HID + col] = f2bf(v);
      }
    }
  }
}

// ---------------- GEMM2: out[tok] += gate * (h @ W2[e] + b2[e]) ----------------
__global__ __launch_bounds__(256, 4) void k_gemm2(
    const unsigned short* __restrict__ h, const unsigned short* __restrict__ w2t,
    const float* __restrict__ b2, const int* __restrict__ slot_token,
    const float* __restrict__ slot_gate, const int* __restrict__ offs,
    float* __restrict__ out) {
  __shared__ unsigned short As[BM*BK];
  __shared__ unsigned short Bs[BN*BK];
  int w = xcd_chunk(blockIdx.x, NMB*NBN2);
  int bm = w / NBN2, bn = w % NBN2;
  int tid = threadIdx.x, wid = tid >> 6, lane = tid & 63;
  int s0 = bm * BM;
  int e = 0;
  #pragma unroll
  for (int i = 1; i < NEXP; ++i) if (s0 >= offs[i]) e = i;
  int kcs = ((lane & 7) ^ (lane >> 3)) * 8;
  int ldst = (lane & 7) * 8;
  const unsigned short* w2te = w2t + ((size_t)e*DIM + (size_t)bn*BN) * HID;

  f32x4 acc[4][4];
  #pragma unroll
  for (int m=0;m<4;m++)
    #pragma unroll
    for (int n=0;n<4;n++) acc[m][n] = (f32x4){0.f,0.f,0.f,0.f};

  int wr = wid >> 1, wc = wid & 1;
  int xr = (lane & 7) * 8;

  for (int kt = 0; kt < HID/BK; ++kt) {
    int k0 = kt * BK;
    #pragma unroll
    for (int i = 0; i < 4; ++i) {
      int r = (i*4 + wid)*8 + (lane >> 3);
      gload_lds16(h + (size_t)(s0 + r)*HID + k0 + kcs, &As[r*BK + ldst]);
      gload_lds16(w2te + (size_t)r*HID + k0 + kcs, &Bs[r*BK + ldst]);
    }
    __syncthreads();
    #pragma unroll
    for (int ks = 0; ks < 2; ++ks) {
      int kk = (ks*32 + (lane >> 4)*8) ^ xr;
      bf16x8 a[4], b[4];
      #pragma unroll
      for (int m=0;m<4;m++) a[m] = *(const bf16x8*)&As[(wr*64 + m*16 + (lane&15))*BK + kk];
      #pragma unroll
      for (int n=0;n<4;n++) b[n] = *(const bf16x8*)&Bs[(wc*64 + n*16 + (lane&15))*BK + kk];
      #pragma unroll
      for (int m=0;m<4;m++)
        #pragma unroll
        for (int n=0;n<4;n++)
          acc[m][n] = __builtin_amdgcn_mfma_f32_16x16x32_bf16(a[m], b[n], acc[m][n], 0,0,0);
    }
    __syncthreads();
  }

  #pragma unroll
  for (int m=0;m<4;m++){
    int rb_ = s0 + wr*64 + m*16 + (lane>>4)*4;
    #pragma unroll
    for (int r=0;r<4;r++){
      int slot = rb_ + r;
      int tok = slot_token[slot];
      if (tok < 0) continue;
      float g = slot_gate[slot];
      #pragma unroll
      for (int n=0;n<4;n++){
        int col = bn*BN + wc*64 + n*16 + (lane&15);
        float v = (acc[m][n][r] + b2[e*DIM + col]) * g;
        atomicAdd(&out[(size_t)tok*DIM + col], v);  // exactly 2 adds/elem -> deterministic
      }
    }
  }
}

extern "C" void kernel_launch(void* const* d_in, const int* in_sizes, int n_in,
                              void* d_out, int out_size, void* d_ws, size_t ws_size,
                              hipStream_t stream) {
  const float* x   = (const float*)d_in[0];
  const float* noi = (const float*)d_in[1];
  const float* Wr  = (const float*)d_in[2];
  const float* br  = (const float*)d_in[3];
  const float* Wn  = (const float*)d_in[4];
  const float* bnb = (const float*)d_in[5];
  const float* W1  = (const float*)d_in[6];
  const float* b1  = (const float*)d_in[7];
  const float* W2  = (const float*)d_in[8];
  const float* b2  = (const float*)d_in[9];
  float* out = (float*)d_out;
  (void)in_sizes; (void)n_in; (void)ws_size;

  char* ws = (char*)d_ws;
  size_t off = 0;
  auto alloc = [&](size_t bytes) -> void* {
    void* p = ws + off; off += (bytes + 255) & ~(size_t)255; return p;
  };
  unsigned short* w1t  = (unsigned short*)alloc((size_t)NEXP*HID*DIM*2);
  unsigned short* w2t  = (unsigned short*)alloc((size_t)NEXP*DIM*HID*2);
  unsigned short* xb   = (unsigned short*)alloc((size_t)N_TOK*DIM*2);
  unsigned short* hbuf = (unsigned short*)alloc((size_t)MAXSLOT*HID*2);
  float* wrt = (float*)alloc(NEXP*DIM*4);
  float* wnt = (float*)alloc(NEXP*DIM*4);
  int*   top_idx  = (int*)alloc(N_TOK*2*4);
  float* top_gate = (float*)alloc(N_TOK*2*4);
  int*   slot_token = (int*)alloc((size_t)MAXSLOT*4);
  float* slot_gate  = (float*)alloc((size_t)MAXSLOT*4);
  int*   ctrl = (int*)alloc(64*4);
  int* counts  = ctrl;        // [10]
  int* cursors = ctrl + 10;   // [10]
  int* offs    = ctrl + 20;   // [11]

  hipMemsetAsync(out, 0, (size_t)out_size*4, stream);
  hipMemsetAsync(ctrl, 0, 64*4, stream);
  hipMemsetAsync(slot_token, 0xFF, (size_t)MAXSLOT*4, stream);  // -1 fill

  k_cvt_x<<<(N_TOK*DIM/8)/256, 256, 0, stream>>>(x, xb);
  k_cvt_router_w<<<(NEXP*DIM+255)/256, 256, 0, stream>>>(Wr, Wn, wrt, wnt);
  k_transpose<<<NEXP*(DIM/64)*(HID/64), 256, 0, stream>>>(W1, w1t, DIM, HID);
  k_transpose<<<NEXP*(HID/64)*(DIM/64), 256, 0, stream>>>(W2, w2t, HID, DIM);
  k_router2<<<N_TOK/RT_TOK, 256, 0, stream>>>(x, noi, wrt, wnt, br, bnb, top_idx, top_gate, counts);
  k_offsets<<<1, 64, 0, stream>>>(counts, cursors, offs);
  k_scatter<<<(N_TOK+255)/256, 256, 0, stream>>>(top_idx, top_gate, cursors, slot_token, slot_gate);
  k_gemm1<<<NMB*NBN1, 256, 0, stream>>>(xb, w1t, b1, slot_token, offs, hbuf);
  k_gemm2<<<NMB*NBN2, 256, 0, stream>>>(hbuf, w2t, b2, slot_token, slot_gate, offs, out);
}